// Round 7
// baseline (103.437 us; speedup 1.0000x reference)
//
#include <hip/hip_runtime.h>
#include <stdint.h>

// Fused NCA step: perception(4 fixed 3x3, wrap) -> 1x1 conv 32->16 +b+ReLU
// -> 1x1 conv 16->8 -> x + y*mask.  fp32, v_pk_fma_f32 (2 px/instr).
// R7: R6 (2-phase LDS pipeline, 96us, VALUBusy 58%) still exposed stage
// latency: __syncthreads drains vmcnt(0) incl. the just-issued stage.
// Now T4 counted-vmcnt depth-2: triple-buffered LDS, stage c+2 after
// barrier c, asm vmcnt(2) + raw s_barrier (never drain-0 in loop).
// All waves issue exactly 2 DMAs/stage (waves 0-2: the 6 row chunks;
// wave 3: mask row) so vmcnt counts are wave-uniform and no global mask
// load pollutes the vmcnt queue.

constexpr int B = 16, C = 8, H = 512, W = 512, HID = 16;
constexpr int HW = H * W;
constexpr int BUF = 3 * W + 512;   // 3 rows + mask copy (floats) = 8 KB

// acc += w * p   (w uniform SGPR pair {w,w}, p/acc per-lane float2)
#define PKFMA_S(acc, w, p) \
    asm("v_pk_fma_f32 %0, %1, %2, %0" : "+v"(acc) : "s"(w), "v"(p))
// acc += a * b   (all VGPR)
#define PKFMA_V(acc, a, b) \
    asm("v_pk_fma_f32 %0, %1, %2, %0" : "+v"(acc) : "v"(a), "v"(b))

#define VMWAIT2 asm volatile("s_waitcnt vmcnt(2)" ::: "memory")
#define VMWAIT0 asm volatile("s_waitcnt vmcnt(0)" ::: "memory")
#define BARRIER do { __builtin_amdgcn_s_barrier(); \
                     __builtin_amdgcn_sched_barrier(0); } while (0)

typedef const __attribute__((address_space(1))) void* as1cp;
typedef __attribute__((address_space(3))) void* as3p;

__global__ void repack_weights(const float* __restrict__ w1w,
                               const float* __restrict__ w2w,
                               float2* __restrict__ wd) {
    const int i = blockIdx.x * 256 + threadIdx.x;
    if (i < 512) {               // w1d[c][h][f] = dup(w1w[h][c*4+f])
        const int c = i >> 6, r = i & 63, h = r >> 2, f = r & 3;
        const float v = w1w[h * 32 + c * 4 + f];
        wd[i] = make_float2(v, v);
    } else if (i < 640) {        // w2d[o][h] = dup(w2w[o][h])
        const float v = w2w[i - 512];
        wd[i] = make_float2(v, v);
    }
}

__global__ __launch_bounds__(256, 6) void nca_step_kernel(
    const float* __restrict__ x,
    const float* __restrict__ w1b,
    const int*   __restrict__ mask,
    float*       __restrict__ out,
    const float2* __restrict__ wd)
{
    __shared__ float S[3 * BUF];             // 24 KB: triple-buffered tile

    // block = one image row; XCD-bijective swizzle (8192 = 8 * 1024)
    const int bid = blockIdx.x;
    const int l   = (bid & 7) * 1024 + (bid >> 3);
    const int b   = l >> 9;
    const int y   = l & (H - 1);

    const int tx   = threadIdx.x;
    const int x0   = tx << 1;                // 2 px/thread
    const int lane = tx & 63;
    const int wv   = tx >> 6;                // wave id 0..3 (uniform per wave)

    const int ym = (y - 1) & (H - 1);
    const int yp = (y + 1) & (H - 1);
    const int xm1 = (x0 - 1) & (W - 1);
    const int xp2 = (x0 + 2) & (W - 1);

    const float* xb = x + (size_t)b * C * HW;
    const int pix = y * W + x0;

    // Stage geometry: every wave issues exactly 2 global_load_lds of 1 KB.
    // w0: (ym,h0)->0, (y,h0)->W      w1: (ym,h1)->256, (y,h1)->W+256
    // w2: (yp,h0)->2W, (yp,h1)->2W+256
    // w3: mask row halves -> 3W, 3W+256 (same data every channel; L2-hot)
    int r1f, l1, r2f, l2;
    if (wv == 0)      { r1f = ym * W;       l1 = 0;       r2f = y * W;        l2 = W; }
    else if (wv == 1) { r1f = ym * W + 256; l1 = 256;     r2f = y * W + 256;  l2 = W + 256; }
    else if (wv == 2) { r1f = yp * W;       l1 = 2 * W;   r2f = yp * W + 256; l2 = 2 * W + 256; }
    else              { r1f = 0;            l1 = 3 * W;   r2f = 256;          l2 = 3 * W + 256; }
    const float* sb = (wv == 3) ? (const float*)(mask + (size_t)b * HW + (size_t)y * W)
                                : xb;
    const int sm = (wv == 3) ? 0 : HW;       // per-channel source stride
    const int g1 = r1f + lane * 4;
    const int g2 = r2f + lane * 4;

#define STAGE(ch, bufo) do {                                               \
    const float* s1_ = sb + (ch) * sm + g1;                                \
    const float* s2_ = sb + (ch) * sm + g2;                                \
    __builtin_amdgcn_global_load_lds((as1cp)s1_, (as3p)(S + (bufo) + l1),  \
                                     16, 0, 0);                            \
    __builtin_amdgcn_global_load_lds((as1cp)s2_, (as3p)(S + (bufo) + l2),  \
                                     16, 0, 0); } while (0)

#define COMPCH(ch, bufo) do {                                              \
    const float* R0 = S + (bufo);                                          \
    const float* R1 = R0 + W;                                              \
    const float* R2 = R1 + W;                                              \
    const float2 vm = *(const float2*)(R0 + x0);                           \
    const float2 vc = *(const float2*)(R1 + x0);                           \
    const float2 vp = *(const float2*)(R2 + x0);                           \
    const float cm[4] = {R0[xm1], vm.x, vm.y, R0[xp2]};                    \
    const float cc[4] = {R1[xm1], vc.x, vc.y, R1[xp2]};                    \
    const float cp[4] = {R2[xm1], vp.x, vp.y, R2[xp2]};                    \
    float s_[4], d_[4];                                                    \
    _Pragma("unroll") for (int i = 0; i < 4; ++i) {                        \
        s_[i] = fmaf(2.0f, cc[i], cm[i] + cp[i]);                          \
        d_[i] = cp[i] - cm[i]; }                                           \
    const float sx0  = (s_[2] - s_[0]) * 0.125f;                           \
    const float sx1  = (s_[3] - s_[1]) * 0.125f;                           \
    const float sy0  = fmaf(2.0f, d_[1], d_[0] + d_[2]) * 0.125f;          \
    const float sy1  = fmaf(2.0f, d_[2], d_[1] + d_[3]) * 0.125f;          \
    const float lap0 = fmaf(fmaf(2.0f, s_[1], s_[0] + s_[2]), 0.0625f, -cc[1]); \
    const float lap1 = fmaf(fmaf(2.0f, s_[2], s_[1] + s_[3]), 0.0625f, -cc[2]); \
    const float2 idn2 = make_float2(cc[1], cc[2]);                         \
    const float2 sx2  = make_float2(sx0, sx1);                             \
    const float2 sy2  = make_float2(sy0, sy1);                             \
    const float2 lp2  = make_float2(lap0, lap1);                           \
    const float2* wch = wd + (ch) * 64;                                    \
    _Pragma("unroll") for (int h = 0; h < HID; ++h) {                      \
        PKFMA_S(acc[h], wch[h * 4 + 0], idn2);                             \
        PKFMA_S(acc[h], wch[h * 4 + 1], sx2);                              \
        PKFMA_S(acc[h], wch[h * 4 + 2], sy2);                              \
        PKFMA_S(acc[h], wch[h * 4 + 3], lp2); } } while (0)

    // prologue: 2 stages in flight before first compute
    STAGE(0, 0);
    STAGE(1, BUF);

    float2 acc[HID];                         // 32 VGPRs, static idx (unrolled)
#pragma unroll
    for (int h = 0; h < HID; ++h) {
        const float bv = w1b[h];             // uniform -> s_load (lgkmcnt)
        acc[h] = make_float2(bv, bv);
    }

    // depth-2 counted pipeline: [vmcnt(2); barrier; stage c+2; compute c]
    // vmcnt(2) retires stage c, leaves c+1/c+2 in flight (queue is pure
    // stage-DMAs: weights are s_loads, mask is staged, no other vmem).
    // Stage c+2 after barrier c is WAR-safe: all readers of buf (c+2)%3
    // consumed their ds_reads before reaching barrier c.
    VMWAIT2; BARRIER; STAGE(2, 2 * BUF); COMPCH(0, 0);
    VMWAIT2; BARRIER; STAGE(3, 0);       COMPCH(1, BUF);
    VMWAIT2; BARRIER; STAGE(4, BUF);     COMPCH(2, 2 * BUF);
    VMWAIT2; BARRIER; STAGE(5, 2 * BUF); COMPCH(3, 0);
    VMWAIT2; BARRIER; STAGE(6, 0);       COMPCH(4, BUF);
    VMWAIT2; BARRIER; STAGE(7, BUF);     COMPCH(5, 2 * BUF);
    VMWAIT2; BARRIER;                    COMPCH(6, 0);
    VMWAIT0; BARRIER;                    COMPCH(7, BUF);

#undef STAGE
#undef COMPCH

    // ReLU
#pragma unroll
    for (int h = 0; h < HID; ++h) {
        acc[h].x = fmaxf(acc[h].x, 0.0f);
        acc[h].y = fmaxf(acc[h].y, 0.0f);
    }

    // mask from the last staged buffer (buf 1, drained by VMWAIT0+barrier)
    const int* mlds = (const int*)(S + BUF + 3 * W);
    const int2 m2 = *(const int2*)(mlds + x0);
    const float2 mf = make_float2((float)m2.x, (float)m2.y);

    const float2* w2d = wd + 512;
    float* ob = out + (size_t)b * C * HW;

    // epilogue: pipelined residual loads (prefetch o+1 under o's 16 pk_fma)
    float2 xo = *(const float2*)(xb + pix);
#pragma unroll
    for (int o = 0; o < C; ++o) {
        float2 xn;
        if (o + 1 < C) xn = *(const float2*)(xb + (o + 1) * HW + pix);
        float2 v = make_float2(0.0f, 0.0f);
#pragma unroll
        for (int h = 0; h < HID; ++h)
            PKFMA_S(v, w2d[o * 16 + h], acc[h]);
        PKFMA_V(xo, v, mf);                   // xo += v * mask
        *(float2*)(ob + o * HW + pix) = xo;
        xo = xn;
    }
}

extern "C" void kernel_launch(void* const* d_in, const int* in_sizes, int n_in,
                              void* d_out, int out_size, void* d_ws, size_t ws_size,
                              hipStream_t stream) {
    const float* x    = (const float*)d_in[0];
    const float* w1w  = (const float*)d_in[1];
    const float* w1b  = (const float*)d_in[2];
    const float* w2w  = (const float*)d_in[3];
    const int*   mask = (const int*)d_in[4];
    float* out = (float*)d_out;
    float2* wd = (float2*)d_ws;              // 640 * 8 B = 5 KiB scratch

    hipLaunchKernelGGL(repack_weights, dim3(3), dim3(256), 0, stream,
                       w1w, w2w, wd);
    hipLaunchKernelGGL(nca_step_kernel, dim3(B * H), dim3(256), 0, stream,
                       x, w1b, mask, out, wd);
}

// Round 8
// 101.905 us; speedup vs baseline: 1.0150x; 1.0150x over previous
//
#include <hip/hip_runtime.h>
#include <stdint.h>

// Fused NCA step: perception(4 fixed 3x3, wrap) -> 1x1 conv 32->16 +b+ReLU
// -> 1x1 conv 16->8 -> x + y*mask.  fp32, v_pk_fma_f32 (2 px/instr).
// R8: R6 (2-phase LDS pipeline, plain __syncthreads, 96us) exposed ~250cyc
// per barrier because 1-channel compute (650cyc) < DMA latency (900cyc).
// R7's counted-vmcnt made it worse (sched pinning). Fix by arithmetic:
//  - 2 channels per phase: compute 1300cyc > 900cyc -> barrier drain free,
//    4 barriers instead of 8; 12 DMA chunks = 3 per wave, uniform.
//  - residual x captured FROM LDS during compute (center row == residual)
//    -> epilogue has zero global loads (saves a full logical x re-read).

constexpr int B = 16, C = 8, H = 512, W = 512, HID = 16;
constexpr int HW = H * W;
constexpr int BUF2 = 2 * 3 * W;        // floats per 2-channel buffer (12 KB)

// acc += w * p   (w uniform SGPR pair {w,w}, p/acc per-lane float2)
#define PKFMA_S(acc, w, p) \
    asm("v_pk_fma_f32 %0, %1, %2, %0" : "+v"(acc) : "s"(w), "v"(p))
// acc += a * b   (all VGPR)
#define PKFMA_V(acc, a, b) \
    asm("v_pk_fma_f32 %0, %1, %2, %0" : "+v"(acc) : "v"(a), "v"(b))

typedef const __attribute__((address_space(1))) void* as1cp;
typedef __attribute__((address_space(3))) void* as3p;

__global__ void repack_weights(const float* __restrict__ w1w,
                               const float* __restrict__ w2w,
                               float2* __restrict__ wd) {
    const int i = blockIdx.x * 256 + threadIdx.x;
    if (i < 512) {               // w1d[c][h][f] = dup(w1w[h][c*4+f])
        const int c = i >> 6, r = i & 63, h = r >> 2, f = r & 3;
        const float v = w1w[h * 32 + c * 4 + f];
        wd[i] = make_float2(v, v);
    } else if (i < 640) {        // w2d[o][h] = dup(w2w[o][h])
        const float v = w2w[i - 512];
        wd[i] = make_float2(v, v);
    }
}

__global__ __launch_bounds__(256, 6) void nca_step_kernel(
    const float* __restrict__ x,
    const float* __restrict__ w1b,
    const int*   __restrict__ mask,
    float*       __restrict__ out,
    const float2* __restrict__ wd)
{
    __shared__ float S[2 * BUF2];            // 24 KB: double 2-channel buffer

    // block = one image row; XCD-bijective swizzle (8192 = 8 * 1024)
    const int bid = blockIdx.x;
    const int l   = (bid & 7) * 1024 + (bid >> 3);
    const int b   = l >> 9;
    const int y   = l & (H - 1);

    const int tx   = threadIdx.x;
    const int x0   = tx << 1;                // 2 px/thread
    const int lane = tx & 63;
    const int wv   = tx >> 6;                // wave id 0..3 (uniform per wave)

    const int ym = (y - 1) & (H - 1);
    const int yp = (y + 1) & (H - 1);
    const int xm1 = (x0 - 1) & (W - 1);
    const int xp2 = (x0 + 2) & (W - 1);

    const float* xb = x + (size_t)b * C * HW;
    const int pix = y * W + x0;

    // mask: one early direct load; latency hidden under the whole pipeline
    const int2 m2 = *(const int2*)(mask + (size_t)b * HW + pix);

    // staging: 2 channels * 3 rows * 512 floats = 12 chunks of 1 KB
    // (64 lanes x 16 B); wave wv carries chunks wv*3 .. wv*3+2.
    // chunk k: channel k/6, row (k%6)>>1 (0=ym,1=y,2=yp), half k&1.
    const int k0 = wv * 3;

#define STAGE2(cb, bufo) do {                                              \
    _Pragma("unroll") for (int j = 0; j < 3; ++j) {                        \
        const int k  = k0 + j;                                             \
        const int ch = k / 6, rr = (k % 6) >> 1, hf = k & 1;               \
        const int grow = (rr == 0) ? ym : ((rr == 1) ? y : yp);            \
        const float* src = xb + ((cb) + ch) * HW + grow * W + hf * 256     \
                              + lane * 4;                                  \
        __builtin_amdgcn_global_load_lds(                                  \
            (as1cp)src,                                                    \
            (as3p)(S + (bufo) + ch * 1536 + rr * 512 + hf * 256),          \
            16, 0, 0);                                                     \
    } } while (0)

#define COMPCH(ch, bufo, cc_) do {                                         \
    const float* R0 = S + (bufo) + (cc_) * 1536;                           \
    const float* R1 = R0 + W;                                              \
    const float* R2 = R1 + W;                                              \
    const float2 vm = *(const float2*)(R0 + x0);                           \
    const float2 vc = *(const float2*)(R1 + x0);                           \
    const float2 vp = *(const float2*)(R2 + x0);                           \
    xs##ch = vc;                      /* residual capture: x[b,ch,y,x0] */ \
    const float cm[4] = {R0[xm1], vm.x, vm.y, R0[xp2]};                    \
    const float cc[4] = {R1[xm1], vc.x, vc.y, R1[xp2]};                    \
    const float cp[4] = {R2[xm1], vp.x, vp.y, R2[xp2]};                    \
    float s_[4], d_[4];                                                    \
    _Pragma("unroll") for (int i = 0; i < 4; ++i) {                        \
        s_[i] = fmaf(2.0f, cc[i], cm[i] + cp[i]);                          \
        d_[i] = cp[i] - cm[i]; }                                           \
    const float sx0  = (s_[2] - s_[0]) * 0.125f;                           \
    const float sx1  = (s_[3] - s_[1]) * 0.125f;                           \
    const float sy0  = fmaf(2.0f, d_[1], d_[0] + d_[2]) * 0.125f;          \
    const float sy1  = fmaf(2.0f, d_[2], d_[1] + d_[3]) * 0.125f;          \
    const float lap0 = fmaf(fmaf(2.0f, s_[1], s_[0] + s_[2]), 0.0625f, -cc[1]); \
    const float lap1 = fmaf(fmaf(2.0f, s_[2], s_[1] + s_[3]), 0.0625f, -cc[2]); \
    const float2 idn2 = make_float2(cc[1], cc[2]);                         \
    const float2 sx2  = make_float2(sx0, sx1);                             \
    const float2 sy2  = make_float2(sy0, sy1);                             \
    const float2 lp2  = make_float2(lap0, lap1);                           \
    const float2* wch = wd + (ch) * 64;                                    \
    _Pragma("unroll") for (int h = 0; h < HID; ++h) {                      \
        PKFMA_S(acc[h], wch[h * 4 + 0], idn2);                             \
        PKFMA_S(acc[h], wch[h * 4 + 1], sx2);                              \
        PKFMA_S(acc[h], wch[h * 4 + 2], sy2);                              \
        PKFMA_S(acc[h], wch[h * 4 + 3], lp2); } } while (0)

    float2 acc[HID];                         // 32 VGPRs, static idx (unrolled)
#pragma unroll
    for (int h = 0; h < HID; ++h) {
        const float bv = w1b[h];             // uniform -> s_load
        acc[h] = make_float2(bv, bv);
    }

    // named residual-capture registers (static, no arrays)
    float2 xs0, xs1, xs2, xs3, xs4, xs5, xs6, xs7;

    // ---- 4-phase pipeline: stage next 2 channels, compute current 2 ----
    STAGE2(0, 0);
    __syncthreads();
    STAGE2(2, BUF2); COMPCH(0, 0, 0);    COMPCH(1, 0, 1);
    __syncthreads();
    STAGE2(4, 0);    COMPCH(2, BUF2, 0); COMPCH(3, BUF2, 1);
    __syncthreads();
    STAGE2(6, BUF2); COMPCH(4, 0, 0);    COMPCH(5, 0, 1);
    __syncthreads();
                     COMPCH(6, BUF2, 0); COMPCH(7, BUF2, 1);

#undef STAGE2
#undef COMPCH

    // ReLU
#pragma unroll
    for (int h = 0; h < HID; ++h) {
        acc[h].x = fmaxf(acc[h].x, 0.0f);
        acc[h].y = fmaxf(acc[h].y, 0.0f);
    }

    const float2 mf = make_float2((float)m2.x, (float)m2.y);
    const float2* w2d = wd + 512;
    float* ob = out + (size_t)b * C * HW;

    // epilogue: conv2 + masked residual add -- ZERO global loads
#define EPI(o, xsv) do {                                                   \
    float2 v = make_float2(0.0f, 0.0f);                                    \
    _Pragma("unroll") for (int h = 0; h < HID; ++h)                        \
        PKFMA_S(v, w2d[(o) * 16 + h], acc[h]);                             \
    float2 r = xsv;                                                        \
    PKFMA_V(r, v, mf);                    /* r = x + conv2 * mask */       \
    *(float2*)(ob + (o) * HW + pix) = r; } while (0)

    EPI(0, xs0); EPI(1, xs1); EPI(2, xs2); EPI(3, xs3);
    EPI(4, xs4); EPI(5, xs5); EPI(6, xs6); EPI(7, xs7);
#undef EPI
}

extern "C" void kernel_launch(void* const* d_in, const int* in_sizes, int n_in,
                              void* d_out, int out_size, void* d_ws, size_t ws_size,
                              hipStream_t stream) {
    const float* x    = (const float*)d_in[0];
    const float* w1w  = (const float*)d_in[1];
    const float* w1b  = (const float*)d_in[2];
    const float* w2w  = (const float*)d_in[3];
    const int*   mask = (const int*)d_in[4];
    float* out = (float*)d_out;
    float2* wd = (float2*)d_ws;              // 640 * 8 B = 5 KiB scratch

    hipLaunchKernelGGL(repack_weights, dim3(3), dim3(256), 0, stream,
                       w1w, w2w, wd);
    hipLaunchKernelGGL(nca_step_kernel, dim3(B * H), dim3(256), 0, stream,
                       x, w1b, mask, out, wd);
}